// Round 8
// baseline (287.710 us; speedup 1.0000x reference)
//
#include <hip/hip_runtime.h>
#include <hip/hip_bf16.h>
#include <math.h>

#define NEGV -9e15f

typedef short bf16x8 __attribute__((ext_vector_type(8)));
typedef float f32x4 __attribute__((ext_vector_type(4)));

__device__ __forceinline__ unsigned short f2bf(float x) {
  unsigned u = __float_as_uint(x);
  u += 0x7fffu + ((u >> 16) & 1u);
  return (unsigned short)(u >> 16);
}

__device__ __forceinline__ unsigned pk2(float a, float b) {
  __hip_bfloat162 h = __float22bfloat162_rn(make_float2(a, b));
  unsigned u;
  __builtin_memcpy(&u, &h, 4);
  return u;
}

// branchless mish: x * n/(n+2), n = u(u+2), u = e^min(x,30)
__device__ __forceinline__ float mishf(float x) {
  float u = __expf(fminf(x, 30.0f));
  float n = u * (u + 2.0f);
  return x * __fdividef(n, n + 2.0f);
}

// ---------------- s[k] = sum_vd v[k][vd] ----------------
__global__ void svec_kernel(const float* __restrict__ v, float* __restrict__ s) {
  int r = blockIdx.x;
  int lane = threadIdx.x;  // 64
  float4 a = *reinterpret_cast<const float4*>(v + (size_t)r * 256 + lane * 4);
  float x = a.x + a.y + a.z + a.w;
  for (int off = 32; off; off >>= 1) x += __shfl_down(x, off);
  if (lane == 0) s[r] = x;
}

// ---------------- M[41][40] = [Wb; bb] @ Wo ----------------
__global__ void mprec_kernel(const float* __restrict__ Wb, const float* __restrict__ bb,
                             const float* __restrict__ Wo, float* __restrict__ M) {
  int i = blockIdx.x;    // 0..40
  int j = threadIdx.x;   // 64 lanes, j<40 active
  if (j >= 40) return;
  float acc = 0.0f;
  for (int k = 0; k < 160; ++k) {
    float w = (i < 40) ? Wb[i * 160 + k] : bb[k];
    acc = fmaf(w, Wo[k * 40 + j], acc);
  }
  M[i * 40 + j] = acc;
}

// ---------------- C[1024x256] = A[1024x256] @ W[256x256] + bvec ----------------
__global__ __launch_bounds__(256) void gemm1024(
    const float* __restrict__ A, const float* __restrict__ W,
    const float* __restrict__ bvec, float* __restrict__ C, int perm) {
  __shared__ float sAT[16][68];
  __shared__ float sW[16][68];
  int tid = threadIdx.x;
  int c0 = blockIdx.x * 64, r0 = blockIdx.y * 64;
  int ty = tid >> 4, tx = tid & 15;
  float acc[4][4] = {};
  for (int k0 = 0; k0 < 256; k0 += 16) {
    {
      int r = tid >> 2, jq = tid & 3;
      float4 a4 = *reinterpret_cast<const float4*>(A + (size_t)(r0 + r) * 256 + k0 + jq * 4);
      sAT[jq * 4 + 0][r] = a4.x;
      sAT[jq * 4 + 1][r] = a4.y;
      sAT[jq * 4 + 2][r] = a4.z;
      sAT[jq * 4 + 3][r] = a4.w;
    }
    {
      int kk = tid >> 4, cq = tid & 15;
      int gk = k0 + kk;
      int row = perm ? ((gk & 63) * 4 + (gk >> 6)) : gk;
      float4 w4 = *reinterpret_cast<const float4*>(W + (size_t)row * 256 + c0 + cq * 4);
      *reinterpret_cast<float4*>(&sW[kk][cq * 4]) = w4;
    }
    __syncthreads();
#pragma unroll
    for (int kk = 0; kk < 16; ++kk) {
      float4 av = *reinterpret_cast<const float4*>(&sAT[kk][ty * 4]);
      float4 bv = *reinterpret_cast<const float4*>(&sW[kk][tx * 4]);
      float a[4] = {av.x, av.y, av.z, av.w};
      float b[4] = {bv.x, bv.y, bv.z, bv.w};
#pragma unroll
      for (int i = 0; i < 4; ++i)
#pragma unroll
        for (int j = 0; j < 4; ++j) acc[i][j] = fmaf(a[i], b[j], acc[i][j]);
    }
    __syncthreads();
  }
#pragma unroll
  for (int i = 0; i < 4; ++i) {
    int rr = r0 + ty * 4 + i, cc = c0 + tx * 4;
    float4 o;
    o.x = acc[i][0] + bvec[cc + 0];
    o.y = acc[i][1] + bvec[cc + 1];
    o.z = acc[i][2] + bvec[cc + 2];
    o.w = acc[i][3] + bvec[cc + 3];
    *reinterpret_cast<float4*>(C + (size_t)rr * 256 + cc) = o;
  }
}

// ---------------- out = LN(x0 + mish(y)) * g + be ----------------
__global__ __launch_bounds__(256) void ln_epilogue(
    const float* __restrict__ x0, const float* __restrict__ y,
    const float* __restrict__ g, const float* __restrict__ be,
    float* __restrict__ out) {
  __shared__ float r1[5], r2[5];
  int r = blockIdx.x, t = threadIdx.x;
  int wid = t >> 6, lane = t & 63;
  float x = x0[(size_t)r * 256 + t] + mishf(y[(size_t)r * 256 + t]);
  float a = x, b = x * x;
  for (int off = 32; off; off >>= 1) {
    a += __shfl_down(a, off);
    b += __shfl_down(b, off);
  }
  if (lane == 0) { r1[wid] = a; r2[wid] = b; }
  __syncthreads();
  if (t == 0) {
    r1[4] = r1[0] + r1[1] + r1[2] + r1[3];
    r2[4] = r2[0] + r2[1] + r2[2] + r2[3];
  }
  __syncthreads();
  float m = r1[4] * (1.0f / 256.0f);
  float var = r2[4] * (1.0f / 256.0f) - m * m;
  out[(size_t)r * 256 + t] = (x - m) * rsqrtf(var + 1e-5f) * g[t] + be[t];
}

// ---------------- fused bias path v2: norms from acc, composite M for bout ----------------
// Per wave: 16 tiles x 16 rows. G1 = mfma(WbT-frag, X-frag) -> accumulators -> per-head
// norms only (no LDS round trip). bout = mish(X @ M + bo) with M = [Wb;bb]@Wo (6 MFMA,
// same X fragments). Weight fragments streamed from LDS tables (conflict-free b128 reads).
__global__ __launch_bounds__(256, 4) void bias_mfma(
    const float* __restrict__ bias, const float* __restrict__ Wb,
    const float* __restrict__ bb, const float* __restrict__ Mmat,
    const float* __restrict__ bo, float* __restrict__ diffs,
    float* __restrict__ bout) {
  __shared__ unsigned short wfL[20 * 64 * 8];  // [n0*2+ks][lane][jj]  20.5 KB
  __shared__ unsigned short mfL[6 * 64 * 8];   // [n*2+ks][lane][jj]    6 KB
  int tid = threadIdx.x;
  int wv = tid >> 6, lane = tid & 63;
  int r = lane & 15, g = lane >> 4;

  // build Wb' fragment table (k=40 slot carries bb)
  for (int idx = tid; idx < 20 * 64; idx += 256) {
    int grp = idx >> 6, lid = idx & 63;
    int n0 = grp >> 1, ks = grp & 1;
    int rr = lid & 15, gg = lid >> 4;
    int c = n0 * 16 + rr;
    unsigned short tmp[8];
#pragma unroll
    for (int jj = 0; jj < 8; ++jj) {
      int k = ks * 32 + gg * 8 + jj;
      float w = (k < 40) ? Wb[k * 160 + c] : ((k == 40) ? bb[c] : 0.0f);
      tmp[jj] = f2bf(w);
    }
    *reinterpret_cast<uint4*>(&wfL[idx * 8]) = *reinterpret_cast<const uint4*>(tmp);
  }
  // build M^T fragment table
  for (int idx = tid; idx < 6 * 64; idx += 256) {
    int grp = idx >> 6, lid = idx & 63;
    int n = grp >> 1, ks = grp & 1;
    int rr = lid & 15, gg = lid >> 4;
    int c = n * 16 + rr;
    unsigned short tmp[8];
#pragma unroll
    for (int jj = 0; jj < 8; ++jj) {
      int k = ks * 32 + gg * 8 + jj;
      float w = (k <= 40 && c < 40) ? Mmat[k * 40 + c] : 0.0f;
      tmp[jj] = f2bf(w);
    }
    *reinterpret_cast<uint4*>(&mfL[idx * 8]) = *reinterpret_cast<const uint4*>(tmp);
  }
  // bo as per-lane float4: cols 16n + 4g .. +3
  f32x4 bo40, bo41, bo42;
  {
    float4 t0 = *reinterpret_cast<const float4*>(bo + 4 * g);
    float4 t1 = *reinterpret_cast<const float4*>(bo + 16 + 4 * g);
    bo40[0] = t0.x; bo40[1] = t0.y; bo40[2] = t0.z; bo40[3] = t0.w;
    bo41[0] = t1.x; bo41[1] = t1.y; bo41[2] = t1.z; bo41[3] = t1.w;
    if (g < 2) {
      float4 t2 = *reinterpret_cast<const float4*>(bo + 32 + 4 * g);
      bo42[0] = t2.x; bo42[1] = t2.y; bo42[2] = t2.z; bo42[3] = t2.w;
    } else {
      bo42[0] = 0.0f; bo42[1] = 0.0f; bo42[2] = 0.0f; bo42[3] = 0.0f;
    }
  }
  __syncthreads();

  size_t row0 = ((size_t)blockIdx.x * 4 + wv) * 256;  // 16 tiles x 16 rows

  // prefetch tile 0
  const float* xr = bias + (row0 + r) * 40;
  float4 xA = *reinterpret_cast<const float4*>(xr + g * 8);
  float4 xB = *reinterpret_cast<const float4*>(xr + g * 8 + 4);
  float4 xC = *reinterpret_cast<const float4*>(xr + 32);
  float4 xD = *reinterpret_cast<const float4*>(xr + 36);

#pragma unroll 1
  for (int t = 0; t < 16; ++t) {
    const size_t p0 = row0 + (size_t)t * 16;
    // X fragments; k=40 slot = 1.0 (bias fold); garbage slots hit zero weights
    bf16x8 xf0, xf1;
    {
      uint4 t0 = {pk2(xA.x, xA.y), pk2(xA.z, xA.w), pk2(xB.x, xB.y), pk2(xB.z, xB.w)};
      unsigned d0 = (g == 1) ? 0x00003f80u : pk2(xC.x, xC.y);
      uint4 t1 = {d0, pk2(xC.z, xC.w), pk2(xD.x, xD.y), pk2(xD.z, xD.w)};
      __builtin_memcpy(&xf0, &t0, 16);
      __builtin_memcpy(&xf1, &t1, 16);
    }
    if (t < 15) {
      const float* xr2 = bias + (p0 + 16 + r) * 40;
      xA = *reinterpret_cast<const float4*>(xr2 + g * 8);
      xB = *reinterpret_cast<const float4*>(xr2 + g * 8 + 4);
      xC = *reinterpret_cast<const float4*>(xr2 + 32);
      xD = *reinterpret_cast<const float4*>(xr2 + 36);
    }
    // G1: P accumulators -> per-quadrant square sums (bb folded in via k=40)
    float cs[10];
#pragma unroll
    for (int n0 = 0; n0 < 10; ++n0) {
      bf16x8 wa = *reinterpret_cast<const bf16x8*>(&wfL[((n0 * 2 + 0) * 64 + lane) * 8]);
      bf16x8 wb2 = *reinterpret_cast<const bf16x8*>(&wfL[((n0 * 2 + 1) * 64 + lane) * 8]);
      f32x4 q = {0.0f, 0.0f, 0.0f, 0.0f};
      q = __builtin_amdgcn_mfma_f32_16x16x32_bf16(wa, xf0, q, 0, 0, 0);
      q = __builtin_amdgcn_mfma_f32_16x16x32_bf16(wb2, xf1, q, 0, 0, 0);
      cs[n0] = q[0] * q[0] + q[1] * q[1] + q[2] * q[2] + q[3] * q[3];
    }
    float hv0 = cs[0] + cs[1] + ((g < 2) ? cs[2] : 0.0f);
    float hv1 = ((g < 2) ? 0.0f : cs[2]) + cs[3] + cs[4];
    float hv2 = cs[5] + cs[6] + ((g < 2) ? cs[7] : 0.0f);
    float hv3 = ((g < 2) ? 0.0f : cs[7]) + cs[8] + cs[9];
    hv0 += __shfl_xor(hv0, 16); hv0 += __shfl_xor(hv0, 32);
    hv1 += __shfl_xor(hv1, 16); hv1 += __shfl_xor(hv1, 32);
    hv2 += __shfl_xor(hv2, 16); hv2 += __shfl_xor(hv2, 32);
    hv3 += __shfl_xor(hv3, 16); hv3 += __shfl_xor(hv3, 32);
    float ss = (g == 0) ? hv0 : (g == 1) ? hv1 : (g == 2) ? hv2 : hv3;
    diffs[(size_t)g * (1024 * 1024) + p0 + r] = sqrtf(ss);
    // G2': OUT = mish(X @ M + bo); lane (r,g) holds OUT[row r][cols 16n+4g..+3]
    f32x4 o0 = bo40, o1 = bo41, o2 = bo42;
    {
      bf16x8 m00 = *reinterpret_cast<const bf16x8*>(&mfL[((0 * 2 + 0) * 64 + lane) * 8]);
      bf16x8 m01 = *reinterpret_cast<const bf16x8*>(&mfL[((0 * 2 + 1) * 64 + lane) * 8]);
      bf16x8 m10 = *reinterpret_cast<const bf16x8*>(&mfL[((1 * 2 + 0) * 64 + lane) * 8]);
      bf16x8 m11 = *reinterpret_cast<const bf16x8*>(&mfL[((1 * 2 + 1) * 64 + lane) * 8]);
      bf16x8 m20 = *reinterpret_cast<const bf16x8*>(&mfL[((2 * 2 + 0) * 64 + lane) * 8]);
      bf16x8 m21 = *reinterpret_cast<const bf16x8*>(&mfL[((2 * 2 + 1) * 64 + lane) * 8]);
      o0 = __builtin_amdgcn_mfma_f32_16x16x32_bf16(m00, xf0, o0, 0, 0, 0);
      o1 = __builtin_amdgcn_mfma_f32_16x16x32_bf16(m10, xf0, o1, 0, 0, 0);
      o2 = __builtin_amdgcn_mfma_f32_16x16x32_bf16(m20, xf0, o2, 0, 0, 0);
      o0 = __builtin_amdgcn_mfma_f32_16x16x32_bf16(m01, xf1, o0, 0, 0, 0);
      o1 = __builtin_amdgcn_mfma_f32_16x16x32_bf16(m11, xf1, o1, 0, 0, 0);
      o2 = __builtin_amdgcn_mfma_f32_16x16x32_bf16(m21, xf1, o2, 0, 0, 0);
    }
    float* bp = bout + (size_t)(p0 + r) * 40;
    float4 st;
    st.x = mishf(o0[0]); st.y = mishf(o0[1]);
    st.z = mishf(o0[2]); st.w = mishf(o0[3]);
    *reinterpret_cast<float4*>(bp + 4 * g) = st;
    st.x = mishf(o1[0]); st.y = mishf(o1[1]);
    st.z = mishf(o1[2]); st.w = mishf(o1[3]);
    *reinterpret_cast<float4*>(bp + 16 + 4 * g) = st;
    if (g < 2) {
      st.x = mishf(o2[0]); st.y = mishf(o2[1]);
      st.z = mishf(o2[2]); st.w = mishf(o2[3]);
      *reinterpret_cast<float4*>(bp + 32 + 4 * g) = st;
    }
  }
}

// ---------------- logits[h][q][k] = qk/8 + diffs, masked (in-place over diffs) ----------------
__global__ __launch_bounds__(256) void scores_kernel(
    const float* __restrict__ pq, const float* __restrict__ pk,
    const int* __restrict__ mask, float* __restrict__ logits) {
  __shared__ float sQT[64][68];
  __shared__ float sKT[64][68];
  int tid = threadIdx.x;
  int k0 = blockIdx.x * 64, q0 = blockIdx.y * 64, h = blockIdx.z;
  for (int i = tid; i < 1024; i += 256) {
    int r = i >> 4, dq = i & 15;
    float4 a = *reinterpret_cast<const float4*>(pq + (size_t)(q0 + r) * 256 + h * 64 + dq * 4);
    sQT[dq * 4 + 0][r] = a.x;
    sQT[dq * 4 + 1][r] = a.y;
    sQT[dq * 4 + 2][r] = a.z;
    sQT[dq * 4 + 3][r] = a.w;
    float4 b = *reinterpret_cast<const float4*>(pk + (size_t)(k0 + r) * 256 + h * 64 + dq * 4);
    sKT[dq * 4 + 0][r] = b.x;
    sKT[dq * 4 + 1][r] = b.y;
    sKT[dq * 4 + 2][r] = b.z;
    sKT[dq * 4 + 3][r] = b.w;
  }
  __syncthreads();
  int ty = tid >> 4, tx = tid & 15;
  float acc[4][4] = {};
#pragma unroll 4
  for (int d = 0; d < 64; ++d) {
    float4 av = *reinterpret_cast<const float4*>(&sQT[d][ty * 4]);
    float4 bv = *reinterpret_cast<const float4*>(&sKT[d][tx * 4]);
    float a[4] = {av.x, av.y, av.z, av.w};
    float b[4] = {bv.x, bv.y, bv.z, bv.w};
#pragma unroll
    for (int i = 0; i < 4; ++i)
#pragma unroll
      for (int j = 0; j < 4; ++j) acc[i][j] = fmaf(a[i], b[j], acc[i][j]);
  }
#pragma unroll
  for (int i = 0; i < 4; ++i) {
    int qq = q0 + ty * 4 + i;
    size_t base = (size_t)h * 1048576 + (size_t)qq * 1024 + k0 + tx * 4;
    float4 dv = *reinterpret_cast<const float4*>(logits + base);
    int4 mv = *reinterpret_cast<const int4*>(mask + (size_t)qq * 1024 + k0 + tx * 4);
    float4 o;
    o.x = (mv.x == 0) ? NEGV : fmaf(acc[i][0], 0.125f, dv.x);
    o.y = (mv.y == 0) ? NEGV : fmaf(acc[i][1], 0.125f, dv.y);
    o.z = (mv.z == 0) ? NEGV : fmaf(acc[i][2], 0.125f, dv.z);
    o.w = (mv.w == 0) ? NEGV : fmaf(acc[i][3], 0.125f, dv.w);
    *reinterpret_cast<float4*>(logits + base) = o;
  }
}

// ---------------- wave per (q, head): softmax over k, dot with s ----------------
__global__ __launch_bounds__(256) void softmax_dot(
    const float* __restrict__ logits, const float* __restrict__ sv,
    float* __restrict__ vm) {
  __shared__ float part[4];
  int q = blockIdx.x;
  int h = threadIdx.x >> 6, lane = threadIdx.x & 63;
  const float* lp = logits + (size_t)h * 1048576 + (size_t)q * 1024;
  float4 lv0 = *reinterpret_cast<const float4*>(lp + lane * 4);
  float4 lv1 = *reinterpret_cast<const float4*>(lp + 256 + lane * 4);
  float4 lv2 = *reinterpret_cast<const float4*>(lp + 512 + lane * 4);
  float4 lv3 = *reinterpret_cast<const float4*>(lp + 768 + lane * 4);
  float4 s0 = *reinterpret_cast<const float4*>(sv + lane * 4);
  float4 s1 = *reinterpret_cast<const float4*>(sv + 256 + lane * 4);
  float4 s2 = *reinterpret_cast<const float4*>(sv + 512 + lane * 4);
  float4 s3 = *reinterpret_cast<const float4*>(sv + 768 + lane * 4);
  float m = fmaxf(fmaxf(fmaxf(lv0.x, lv0.y), fmaxf(lv0.z, lv0.w)),
                  fmaxf(fmaxf(lv1.x, lv1.y), fmaxf(lv1.z, lv1.w)));
  m = fmaxf(m, fmaxf(fmaxf(fmaxf(lv2.x, lv2.y), fmaxf(lv2.z, lv2.w)),
                     fmaxf(fmaxf(lv3.x, lv3.y), fmaxf(lv3.z, lv3.w))));
#pragma unroll
  for (int off = 32; off; off >>= 1) m = fmaxf(m, __shfl_xor(m, off));
  float ps = 0.0f, pd = 0.0f;
  {
    float e;
    e = __expf(lv0.x - m); ps += e; pd = fmaf(e, s0.x, pd);
    e = __expf(lv0.y - m); ps += e; pd = fmaf(e, s0.y, pd);
    e = __expf(lv0.z - m); ps += e; pd = fmaf(e, s0.z, pd);
    e = __expf(lv0.w - m); ps += e; pd = fmaf(e, s0.w, pd);
    e = __expf(lv1.x - m); ps += e; pd = fmaf(e, s1.x, pd);
    e = __expf(lv1.y - m); ps += e; pd = fmaf(e, s1.y, pd);
    e = __expf(lv1.z - m); ps += e; pd = fmaf(e, s1.z, pd);
    e = __expf(lv1.w - m); ps += e; pd = fmaf(e, s1.w, pd);
    e = __expf(lv2.x - m); ps += e; pd = fmaf(e, s2.x, pd);
    e = __expf(lv2.y - m); ps += e; pd = fmaf(e, s2.y, pd);
    e = __expf(lv2.z - m); ps += e; pd = fmaf(e, s2.z, pd);
    e = __expf(lv2.w - m); ps += e; pd = fmaf(e, s2.w, pd);
    e = __expf(lv3.x - m); ps += e; pd = fmaf(e, s3.x, pd);
    e = __expf(lv3.y - m); ps += e; pd = fmaf(e, s3.y, pd);
    e = __expf(lv3.z - m); ps += e; pd = fmaf(e, s3.z, pd);
    e = __expf(lv3.w - m); ps += e; pd = fmaf(e, s3.w, pd);
  }
#pragma unroll
  for (int off = 32; off; off >>= 1) {
    ps += __shfl_xor(ps, off);
    pd += __shfl_xor(pd, off);
  }
  if (lane == 0) part[h] = pd / ps;
  __syncthreads();
  if (threadIdx.x == 0)
    vm[q] = (part[0] + part[1] + part[2] + part[3]) * (1.0f / 1024.0f);
}

extern "C" void kernel_launch(void* const* d_in, const int* in_sizes, int n_in,
                              void* d_out, int out_size, void* d_ws, size_t ws_size,
                              hipStream_t stream) {
  const float* q     = (const float*)d_in[0];
  const float* k     = (const float*)d_in[1];
  const float* v     = (const float*)d_in[2];
  const float* bias  = (const float*)d_in[3];
  const int*   mask  = (const int*)d_in[4];
  const float* Wq    = (const float*)d_in[5];
  const float* bq    = (const float*)d_in[6];
  const float* Wk    = (const float*)d_in[7];
  const float* bk    = (const float*)d_in[8];
  const float* Wbias = (const float*)d_in[9];
  const float* bbias = (const float*)d_in[10];
  const float* Wqo   = (const float*)d_in[11];
  const float* bqo   = (const float*)d_in[12];
  const float* Wko   = (const float*)d_in[13];
  const float* bko   = (const float*)d_in[14];
  const float* g_q   = (const float*)d_in[15];
  const float* be_q  = (const float*)d_in[16];
  const float* g_k   = (const float*)d_in[17];
  const float* be_k  = (const float*)d_in[18];
  const float* Wbo   = (const float*)d_in[19];
  const float* bbo   = (const float*)d_in[20];

  float* out = (float*)d_out;
  float* ws  = (float*)d_ws;
  float* projq = ws;                 // 1024x256
  float* projk = ws + 262144;        // 1024x256
  float* qo    = ws + 524288;        // 1024x256
  float* ko    = ws + 786432;        // 1024x256
  float* diffs = ws + 1048576;       // 4 x 1024 x 1024 (reused in-place as logits)
  float* svec  = ws + 5242880;       // 1024
  float* Mmat  = ws + 5243904;       // 41 x 40 composite

  float* q_out    = out;             // 1024x256
  float* k_out    = out + 262144;    // 1024x256
  float* vmean    = out + 524288;    // 1024
  float* bias_out = out + 525312;    // 1024x1024x40

  svec_kernel<<<1024, 64, 0, stream>>>(v, svec);
  mprec_kernel<<<41, 64, 0, stream>>>(Wbias, bbias, Wbo, Mmat);
  gemm1024<<<dim3(4, 16), 256, 0, stream>>>(q, Wq, bq, projq, 0);
  gemm1024<<<dim3(4, 16), 256, 0, stream>>>(k, Wk, bk, projk, 0);
  gemm1024<<<dim3(4, 16), 256, 0, stream>>>(projq, Wqo, bqo, qo, 1);
  gemm1024<<<dim3(4, 16), 256, 0, stream>>>(projk, Wko, bko, ko, 1);
  ln_epilogue<<<1024, 256, 0, stream>>>(q, qo, g_q, be_q, q_out);
  ln_epilogue<<<1024, 256, 0, stream>>>(k, ko, g_k, be_k, k_out);
  bias_mfma<<<1024, 256, 0, stream>>>(bias, Wbias, bbias, Mmat, bbo, diffs, bias_out);
  scores_kernel<<<dim3(16, 16, 4), 256, 0, stream>>>(projq, projk, mask, diffs);
  softmax_dot<<<1024, 256, 0, stream>>>(diffs, svec, vmean);
}

// Round 9
// 219.844 us; speedup vs baseline: 1.3087x; 1.3087x over previous
//
#include <hip/hip_runtime.h>
#include <hip/hip_bf16.h>
#include <math.h>

#define NEGV -9e15f

typedef short bf16x8 __attribute__((ext_vector_type(8)));
typedef float f32x4 __attribute__((ext_vector_type(4)));

__device__ __forceinline__ unsigned short f2bf(float x) {
  unsigned u = __float_as_uint(x);
  u += 0x7fffu + ((u >> 16) & 1u);
  return (unsigned short)(u >> 16);
}

__device__ __forceinline__ unsigned pk2(float a, float b) {
  __hip_bfloat162 h = __float22bfloat162_rn(make_float2(a, b));
  unsigned u;
  __builtin_memcpy(&u, &h, 4);
  return u;
}

// branchless mish: x * n/(n+2), n = u(u+2), u = e^min(x,30)
__device__ __forceinline__ float mishf(float x) {
  float u = __expf(fminf(x, 30.0f));
  float n = u * (u + 2.0f);
  return x * __fdividef(n, n + 2.0f);
}

// ---------------- s[k] = sum_vd v[k][vd] ----------------
__global__ void svec_kernel(const float* __restrict__ v, float* __restrict__ s) {
  int r = blockIdx.x;
  int lane = threadIdx.x;  // 64
  float4 a = *reinterpret_cast<const float4*>(v + (size_t)r * 256 + lane * 4);
  float x = a.x + a.y + a.z + a.w;
  for (int off = 32; off; off >>= 1) x += __shfl_down(x, off);
  if (lane == 0) s[r] = x;
}

// ---------------- M[41][40] = [Wb; bb] @ Wo ----------------
__global__ void mprec_kernel(const float* __restrict__ Wb, const float* __restrict__ bb,
                             const float* __restrict__ Wo, float* __restrict__ M) {
  int i = blockIdx.x;    // 0..40
  int j = threadIdx.x;   // 64 lanes, j<40 active
  if (j >= 40) return;
  float acc = 0.0f;
  for (int k = 0; k < 160; ++k) {
    float w = (i < 40) ? Wb[i * 160 + k] : bb[k];
    acc = fmaf(w, Wo[k * 40 + j], acc);
  }
  M[i * 40 + j] = acc;
}

// ---------------- C[1024x256] = A[1024x256] @ W[256x256] + bvec ----------------
__global__ __launch_bounds__(256) void gemm1024(
    const float* __restrict__ A, const float* __restrict__ W,
    const float* __restrict__ bvec, float* __restrict__ C, int perm) {
  __shared__ float sAT[16][68];
  __shared__ float sW[16][68];
  int tid = threadIdx.x;
  int c0 = blockIdx.x * 64, r0 = blockIdx.y * 64;
  int ty = tid >> 4, tx = tid & 15;
  float acc[4][4] = {};
  for (int k0 = 0; k0 < 256; k0 += 16) {
    {
      int r = tid >> 2, jq = tid & 3;
      float4 a4 = *reinterpret_cast<const float4*>(A + (size_t)(r0 + r) * 256 + k0 + jq * 4);
      sAT[jq * 4 + 0][r] = a4.x;
      sAT[jq * 4 + 1][r] = a4.y;
      sAT[jq * 4 + 2][r] = a4.z;
      sAT[jq * 4 + 3][r] = a4.w;
    }
    {
      int kk = tid >> 4, cq = tid & 15;
      int gk = k0 + kk;
      int row = perm ? ((gk & 63) * 4 + (gk >> 6)) : gk;
      float4 w4 = *reinterpret_cast<const float4*>(W + (size_t)row * 256 + c0 + cq * 4);
      *reinterpret_cast<float4*>(&sW[kk][cq * 4]) = w4;
    }
    __syncthreads();
#pragma unroll
    for (int kk = 0; kk < 16; ++kk) {
      float4 av = *reinterpret_cast<const float4*>(&sAT[kk][ty * 4]);
      float4 bv = *reinterpret_cast<const float4*>(&sW[kk][tx * 4]);
      float a[4] = {av.x, av.y, av.z, av.w};
      float b[4] = {bv.x, bv.y, bv.z, bv.w};
#pragma unroll
      for (int i = 0; i < 4; ++i)
#pragma unroll
        for (int j = 0; j < 4; ++j) acc[i][j] = fmaf(a[i], b[j], acc[i][j]);
    }
    __syncthreads();
  }
#pragma unroll
  for (int i = 0; i < 4; ++i) {
    int rr = r0 + ty * 4 + i, cc = c0 + tx * 4;
    float4 o;
    o.x = acc[i][0] + bvec[cc + 0];
    o.y = acc[i][1] + bvec[cc + 1];
    o.z = acc[i][2] + bvec[cc + 2];
    o.w = acc[i][3] + bvec[cc + 3];
    *reinterpret_cast<float4*>(C + (size_t)rr * 256 + cc) = o;
  }
}

// ---------------- out = LN(x0 + mish(y)) * g + be ----------------
__global__ __launch_bounds__(256) void ln_epilogue(
    const float* __restrict__ x0, const float* __restrict__ y,
    const float* __restrict__ g, const float* __restrict__ be,
    float* __restrict__ out) {
  __shared__ float r1[5], r2[5];
  int r = blockIdx.x, t = threadIdx.x;
  int wid = t >> 6, lane = t & 63;
  float x = x0[(size_t)r * 256 + t] + mishf(y[(size_t)r * 256 + t]);
  float a = x, b = x * x;
  for (int off = 32; off; off >>= 1) {
    a += __shfl_down(a, off);
    b += __shfl_down(b, off);
  }
  if (lane == 0) { r1[wid] = a; r2[wid] = b; }
  __syncthreads();
  if (t == 0) {
    r1[4] = r1[0] + r1[1] + r1[2] + r1[3];
    r2[4] = r2[0] + r2[1] + r2[2] + r2[3];
  }
  __syncthreads();
  float m = r1[4] * (1.0f / 256.0f);
  float var = r2[4] * (1.0f / 256.0f) - m * m;
  out[(size_t)r * 256 + t] = (x - m) * rsqrtf(var + 1e-5f) * g[t] + be[t];
}

// ---------------- fused bias path v3: regs-only, 2 tiles/iter for MLP+ILP ----------------
// G1 = mfma(Wb'-frag, X-frag): norms straight from accumulators.
// bout = mish(X @ M + bo), M = [Wb;bb]@Wo composite (6 MFMA, same X fragments).
// Zero LDS in the main loop; all weights in registers; 2 waves/SIMD regime.

// one tile: G1 norms + diffs store + G2' + mish + bout stores
#define TILE_BODY(XF0, XF1, P0) do {                                                   \
    float hv0, hv1, hv2, hv3;                                                          \
    {                                                                                  \
      f32x4 z = {0.0f, 0.0f, 0.0f, 0.0f};                                              \
      f32x4 q;                                                                         \
      float cs2, cs7;                                                                  \
      q = __builtin_amdgcn_mfma_f32_16x16x32_bf16(wf[0][0], XF0, z, 0, 0, 0);          \
      q = __builtin_amdgcn_mfma_f32_16x16x32_bf16(wf[0][1], XF1, q, 0, 0, 0);          \
      hv0 = q[0]*q[0] + q[1]*q[1] + q[2]*q[2] + q[3]*q[3];                             \
      q = __builtin_amdgcn_mfma_f32_16x16x32_bf16(wf[1][0], XF0, z, 0, 0, 0);          \
      q = __builtin_amdgcn_mfma_f32_16x16x32_bf16(wf[1][1], XF1, q, 0, 0, 0);          \
      hv0 += q[0]*q[0] + q[1]*q[1] + q[2]*q[2] + q[3]*q[3];                            \
      q = __builtin_amdgcn_mfma_f32_16x16x32_bf16(wf[2][0], XF0, z, 0, 0, 0);          \
      q = __builtin_amdgcn_mfma_f32_16x16x32_bf16(wf[2][1], XF1, q, 0, 0, 0);          \
      cs2 = q[0]*q[0] + q[1]*q[1] + q[2]*q[2] + q[3]*q[3];                             \
      q = __builtin_amdgcn_mfma_f32_16x16x32_bf16(wf[3][0], XF0, z, 0, 0, 0);          \
      q = __builtin_amdgcn_mfma_f32_16x16x32_bf16(wf[3][1], XF1, q, 0, 0, 0);          \
      hv1 = q[0]*q[0] + q[1]*q[1] + q[2]*q[2] + q[3]*q[3];                             \
      q = __builtin_amdgcn_mfma_f32_16x16x32_bf16(wf[4][0], XF0, z, 0, 0, 0);          \
      q = __builtin_amdgcn_mfma_f32_16x16x32_bf16(wf[4][1], XF1, q, 0, 0, 0);          \
      hv1 += q[0]*q[0] + q[1]*q[1] + q[2]*q[2] + q[3]*q[3];                            \
      q = __builtin_amdgcn_mfma_f32_16x16x32_bf16(wf[5][0], XF0, z, 0, 0, 0);          \
      q = __builtin_amdgcn_mfma_f32_16x16x32_bf16(wf[5][1], XF1, q, 0, 0, 0);          \
      hv2 = q[0]*q[0] + q[1]*q[1] + q[2]*q[2] + q[3]*q[3];                             \
      q = __builtin_amdgcn_mfma_f32_16x16x32_bf16(wf[6][0], XF0, z, 0, 0, 0);          \
      q = __builtin_amdgcn_mfma_f32_16x16x32_bf16(wf[6][1], XF1, q, 0, 0, 0);          \
      hv2 += q[0]*q[0] + q[1]*q[1] + q[2]*q[2] + q[3]*q[3];                            \
      q = __builtin_amdgcn_mfma_f32_16x16x32_bf16(wf[7][0], XF0, z, 0, 0, 0);          \
      q = __builtin_amdgcn_mfma_f32_16x16x32_bf16(wf[7][1], XF1, q, 0, 0, 0);          \
      cs7 = q[0]*q[0] + q[1]*q[1] + q[2]*q[2] + q[3]*q[3];                             \
      q = __builtin_amdgcn_mfma_f32_16x16x32_bf16(wf[8][0], XF0, z, 0, 0, 0);          \
      q = __builtin_amdgcn_mfma_f32_16x16x32_bf16(wf[8][1], XF1, q, 0, 0, 0);          \
      hv3 = q[0]*q[0] + q[1]*q[1] + q[2]*q[2] + q[3]*q[3];                             \
      q = __builtin_amdgcn_mfma_f32_16x16x32_bf16(wf[9][0], XF0, z, 0, 0, 0);          \
      q = __builtin_amdgcn_mfma_f32_16x16x32_bf16(wf[9][1], XF1, q, 0, 0, 0);          \
      hv3 += q[0]*q[0] + q[1]*q[1] + q[2]*q[2] + q[3]*q[3];                            \
      float csa = (g < 2) ? cs2 : 0.0f;                                                \
      float csb = (g < 2) ? 0.0f : cs2;                                                \
      float csc = (g < 2) ? cs7 : 0.0f;                                                \
      float csd = (g < 2) ? 0.0f : cs7;                                                \
      hv0 += csa; hv1 += csb; hv2 += csc; hv3 += csd;                                  \
    }                                                                                  \
    hv0 += __shfl_xor(hv0, 16); hv0 += __shfl_xor(hv0, 32);                            \
    hv1 += __shfl_xor(hv1, 16); hv1 += __shfl_xor(hv1, 32);                            \
    hv2 += __shfl_xor(hv2, 16); hv2 += __shfl_xor(hv2, 32);                            \
    hv3 += __shfl_xor(hv3, 16); hv3 += __shfl_xor(hv3, 32);                            \
    float ss = (g == 0) ? hv0 : (g == 1) ? hv1 : (g == 2) ? hv2 : hv3;                 \
    diffs[(size_t)g * (1024 * 1024) + (P0) + r] = sqrtf(ss);                           \
    f32x4 o0 = bo40, o1 = bo41, o2 = bo42;                                             \
    o0 = __builtin_amdgcn_mfma_f32_16x16x32_bf16(mf[0][0], XF0, o0, 0, 0, 0);          \
    o1 = __builtin_amdgcn_mfma_f32_16x16x32_bf16(mf[1][0], XF0, o1, 0, 0, 0);          \
    o2 = __builtin_amdgcn_mfma_f32_16x16x32_bf16(mf[2][0], XF0, o2, 0, 0, 0);          \
    o0 = __builtin_amdgcn_mfma_f32_16x16x32_bf16(mf[0][1], XF1, o0, 0, 0, 0);          \
    o1 = __builtin_amdgcn_mfma_f32_16x16x32_bf16(mf[1][1], XF1, o1, 0, 0, 0);          \
    o2 = __builtin_amdgcn_mfma_f32_16x16x32_bf16(mf[2][1], XF1, o2, 0, 0, 0);          \
    float* bp = bout + (size_t)((P0) + r) * 40;                                        \
    float4 st;                                                                         \
    st.x = mishf(o0[0]); st.y = mishf(o0[1]);                                          \
    st.z = mishf(o0[2]); st.w = mishf(o0[3]);                                          \
    *reinterpret_cast<float4*>(bp + 4 * g) = st;                                       \
    st.x = mishf(o1[0]); st.y = mishf(o1[1]);                                          \
    st.z = mishf(o1[2]); st.w = mishf(o1[3]);                                          \
    *reinterpret_cast<float4*>(bp + 16 + 4 * g) = st;                                  \
    if (g < 2) {                                                                       \
      st.x = mishf(o2[0]); st.y = mishf(o2[1]);                                        \
      st.z = mishf(o2[2]); st.w = mishf(o2[3]);                                        \
      *reinterpret_cast<float4*>(bp + 32 + 4 * g) = st;                                \
    }                                                                                  \
  } while (0)

__global__ __launch_bounds__(256, 2) void bias_mfma(
    const float* __restrict__ bias, const float* __restrict__ Wb,
    const float* __restrict__ bb, const float* __restrict__ Mmat,
    const float* __restrict__ bo, float* __restrict__ diffs,
    float* __restrict__ bout) {
  int tid = threadIdx.x;
  int wv = tid >> 6, lane = tid & 63;
  int r = lane & 15, g = lane >> 4;

  // Wb' fragments (A-operand): wf[n0][ks]; k=40 slot carries bb (bias fold)
  bf16x8 wf[10][2];
#pragma unroll
  for (int n0 = 0; n0 < 10; ++n0)
#pragma unroll
    for (int ks = 0; ks < 2; ++ks)
#pragma unroll
      for (int jj = 0; jj < 8; ++jj) {
        int k = ks * 32 + g * 8 + jj;
        int c = n0 * 16 + r;
        float w = (k < 40) ? Wb[k * 160 + c] : ((k == 40) ? bb[c] : 0.0f);
        wf[n0][ks][jj] = (short)f2bf(w);
      }
  // M^T fragments (A-operand): mf[n][ks]
  bf16x8 mf[3][2];
#pragma unroll
  for (int n = 0; n < 3; ++n)
#pragma unroll
    for (int ks = 0; ks < 2; ++ks)
#pragma unroll
      for (int jj = 0; jj < 8; ++jj) {
        int k = ks * 32 + g * 8 + jj;
        int c = n * 16 + r;
        float w = (k <= 40 && c < 40) ? Mmat[k * 40 + c] : 0.0f;
        mf[n][ks][jj] = (short)f2bf(w);
      }
  // bo as per-lane f32x4: cols 16n + 4g .. +3
  f32x4 bo40, bo41, bo42;
  {
    float4 t0 = *reinterpret_cast<const float4*>(bo + 4 * g);
    float4 t1 = *reinterpret_cast<const float4*>(bo + 16 + 4 * g);
    bo40[0] = t0.x; bo40[1] = t0.y; bo40[2] = t0.z; bo40[3] = t0.w;
    bo41[0] = t1.x; bo41[1] = t1.y; bo41[2] = t1.z; bo41[3] = t1.w;
    if (g < 2) {
      float4 t2 = *reinterpret_cast<const float4*>(bo + 32 + 4 * g);
      bo42[0] = t2.x; bo42[1] = t2.y; bo42[2] = t2.z; bo42[3] = t2.w;
    } else {
      bo42[0] = 0.0f; bo42[1] = 0.0f; bo42[2] = 0.0f; bo42[3] = 0.0f;
    }
  }

  size_t row0 = ((size_t)blockIdx.x * 4 + wv) * 256;  // 8 iters x 2 tiles x 16 rows

  // prefetch tiles 0,1
  const float* xr0 = bias + (row0 + r) * 40;
  const float* xr1 = bias + (row0 + 16 + r) * 40;
  float4 x0A = *reinterpret_cast<const float4*>(xr0 + g * 8);
  float4 x0B = *reinterpret_cast<const float4*>(xr0 + g * 8 + 4);
  float4 x0C = *reinterpret_cast<const float4*>(xr0 + 32);
  float4 x0D = *reinterpret_cast<const float4*>(xr0 + 36);
  float4 x1A = *reinterpret_cast<const float4*>(xr1 + g * 8);
  float4 x1B = *reinterpret_cast<const float4*>(xr1 + g * 8 + 4);
  float4 x1C = *reinterpret_cast<const float4*>(xr1 + 32);
  float4 x1D = *reinterpret_cast<const float4*>(xr1 + 36);

#pragma unroll 1
  for (int it = 0; it < 8; ++it) {
    const size_t p0 = row0 + (size_t)it * 32;
    // build X fragments for both tiles; k=40 slot = 1.0 (bias fold)
    bf16x8 a0f0, a0f1, a1f0, a1f1;
    {
      uint4 t0 = {pk2(x0A.x, x0A.y), pk2(x0A.z, x0A.w), pk2(x0B.x, x0B.y), pk2(x0B.z, x0B.w)};
      unsigned d0 = (g == 1) ? 0x00003f80u : pk2(x0C.x, x0C.y);
      uint4 t1 = {d0, pk2(x0C.z, x0C.w), pk2(x0D.x, x0D.y), pk2(x0D.z, x0D.w)};
      __builtin_memcpy(&a0f0, &t0, 16);
      __builtin_memcpy(&a0f1, &t1, 16);
      uint4 t2 = {pk2(x1A.x, x1A.y), pk2(x1A.z, x1A.w), pk2(x1B.x, x1B.y), pk2(x1B.z, x1B.w)};
      unsigned d1 = (g == 1) ? 0x00003f80u : pk2(x1C.x, x1C.y);
      uint4 t3 = {d1, pk2(x1C.z, x1C.w), pk2(x1D.x, x1D.y), pk2(x1D.z, x1D.w)};
      __builtin_memcpy(&a1f0, &t2, 16);
      __builtin_memcpy(&a1f1, &t3, 16);
    }
    // prefetch next pair
    if (it < 7) {
      const float* nr0 = bias + (p0 + 32 + r) * 40;
      const float* nr1 = bias + (p0 + 48 + r) * 40;
      x0A = *reinterpret_cast<const float4*>(nr0 + g * 8);
      x0B = *reinterpret_cast<const float4*>(nr0 + g * 8 + 4);
      x0C = *reinterpret_cast<const float4*>(nr0 + 32);
      x0D = *reinterpret_cast<const float4*>(nr0 + 36);
      x1A = *reinterpret_cast<const float4*>(nr1 + g * 8);
      x1B = *reinterpret_cast<const float4*>(nr1 + g * 8 + 4);
      x1C = *reinterpret_cast<const float4*>(nr1 + 32);
      x1D = *reinterpret_cast<const float4*>(nr1 + 36);
    }
    TILE_BODY(a0f0, a0f1, p0);
    TILE_BODY(a1f0, a1f1, p0 + 16);
  }
}

// ---------------- logits[h][q][k] = qk/8 + diffs, masked (in-place over diffs) ----------------
__global__ __launch_bounds__(256) void scores_kernel(
    const float* __restrict__ pq, const float* __restrict__ pk,
    const int* __restrict__ mask, float* __restrict__ logits) {
  __shared__ float sQT[64][68];
  __shared__ float sKT[64][68];
  int tid = threadIdx.x;
  int k0 = blockIdx.x * 64, q0 = blockIdx.y * 64, h = blockIdx.z;
  for (int i = tid; i < 1024; i += 256) {
    int r = i >> 4, dq = i & 15;
    float4 a = *reinterpret_cast<const float4*>(pq + (size_t)(q0 + r) * 256 + h * 64 + dq * 4);
    sQT[dq * 4 + 0][r] = a.x;
    sQT[dq * 4 + 1][r] = a.y;
    sQT[dq * 4 + 2][r] = a.z;
    sQT[dq * 4 + 3][r] = a.w;
    float4 b = *reinterpret_cast<const float4*>(pk + (size_t)(k0 + r) * 256 + h * 64 + dq * 4);
    sKT[dq * 4 + 0][r] = b.x;
    sKT[dq * 4 + 1][r] = b.y;
    sKT[dq * 4 + 2][r] = b.z;
    sKT[dq * 4 + 3][r] = b.w;
  }
  __syncthreads();
  int ty = tid >> 4, tx = tid & 15;
  float acc[4][4] = {};
#pragma unroll 4
  for (int d = 0; d < 64; ++d) {
    float4 av = *reinterpret_cast<const float4*>(&sQT[d][ty * 4]);
    float4 bv = *reinterpret_cast<const float4*>(&sKT[d][tx * 4]);
    float a[4] = {av.x, av.y, av.z, av.w};
    float b[4] = {bv.x, bv.y, bv.z, bv.w};
#pragma unroll
    for (int i = 0; i < 4; ++i)
#pragma unroll
      for (int j = 0; j < 4; ++j) acc[i][j] = fmaf(a[i], b[j], acc[i][j]);
  }
#pragma unroll
  for (int i = 0; i < 4; ++i) {
    int qq = q0 + ty * 4 + i;
    size_t base = (size_t)h * 1048576 + (size_t)qq * 1024 + k0 + tx * 4;
    float4 dv = *reinterpret_cast<const float4*>(logits + base);
    int4 mv = *reinterpret_cast<const int4*>(mask + (size_t)qq * 1024 + k0 + tx * 4);
    float4 o;
    o.x = (mv.x == 0) ? NEGV : fmaf(acc[i][0], 0.125f, dv.x);
    o.y = (mv.y == 0) ? NEGV : fmaf(acc[i][1], 0.125f, dv.y);
    o.z = (mv.z == 0) ? NEGV : fmaf(acc[i][2], 0.125f, dv.z);
    o.w = (mv.w == 0) ? NEGV : fmaf(acc[i][3], 0.125f, dv.w);
    *reinterpret_cast<float4*>(logits + base) = o;
  }
}

// ---------------- wave per (q, head): softmax over k, dot with s ----------------
__global__ __launch_bounds__(256) void softmax_dot(
    const float* __restrict__ logits, const float* __restrict__ sv,
    float* __restrict__ vm) {
  __shared__ float part[4];
  int q = blockIdx.x;
  int h = threadIdx.x >> 6, lane = threadIdx.x & 63;
  const float* lp = logits + (size_t)h * 1048576 + (size_t)q * 1024;
  float4 lv0 = *reinterpret_cast<const float4*>(lp + lane * 4);
  float4 lv1 = *reinterpret_cast<const float4*>(lp + 256 + lane * 4);
  float4 lv2 = *reinterpret_cast<const float4*>(lp + 512 + lane * 4);
  float4 lv3 = *reinterpret_cast<const float4*>(lp + 768 + lane * 4);
  float4 s0 = *reinterpret_cast<const float4*>(sv + lane * 4);
  float4 s1 = *reinterpret_cast<const float4*>(sv + 256 + lane * 4);
  float4 s2 = *reinterpret_cast<const float4*>(sv + 512 + lane * 4);
  float4 s3 = *reinterpret_cast<const float4*>(sv + 768 + lane * 4);
  float m = fmaxf(fmaxf(fmaxf(lv0.x, lv0.y), fmaxf(lv0.z, lv0.w)),
                  fmaxf(fmaxf(lv1.x, lv1.y), fmaxf(lv1.z, lv1.w)));
  m = fmaxf(m, fmaxf(fmaxf(fmaxf(lv2.x, lv2.y), fmaxf(lv2.z, lv2.w)),
                     fmaxf(fmaxf(lv3.x, lv3.y), fmaxf(lv3.z, lv3.w))));
#pragma unroll
  for (int off = 32; off; off >>= 1) m = fmaxf(m, __shfl_xor(m, off));
  float ps = 0.0f, pd = 0.0f;
  {
    float e;
    e = __expf(lv0.x - m); ps += e; pd = fmaf(e, s0.x, pd);
    e = __expf(lv0.y - m); ps += e; pd = fmaf(e, s0.y, pd);
    e = __expf(lv0.z - m); ps += e; pd = fmaf(e, s0.z, pd);
    e = __expf(lv0.w - m); ps += e; pd = fmaf(e, s0.w, pd);
    e = __expf(lv1.x - m); ps += e; pd = fmaf(e, s1.x, pd);
    e = __expf(lv1.y - m); ps += e; pd = fmaf(e, s1.y, pd);
    e = __expf(lv1.z - m); ps += e; pd = fmaf(e, s1.z, pd);
    e = __expf(lv1.w - m); ps += e; pd = fmaf(e, s1.w, pd);
    e = __expf(lv2.x - m); ps += e; pd = fmaf(e, s2.x, pd);
    e = __expf(lv2.y - m); ps += e; pd = fmaf(e, s2.y, pd);
    e = __expf(lv2.z - m); ps += e; pd = fmaf(e, s2.z, pd);
    e = __expf(lv2.w - m); ps += e; pd = fmaf(e, s2.w, pd);
    e = __expf(lv3.x - m); ps += e; pd = fmaf(e, s3.x, pd);
    e = __expf(lv3.y - m); ps += e; pd = fmaf(e, s3.y, pd);
    e = __expf(lv3.z - m); ps += e; pd = fmaf(e, s3.z, pd);
    e = __expf(lv3.w - m); ps += e; pd = fmaf(e, s3.w, pd);
  }
#pragma unroll
  for (int off = 32; off; off >>= 1) {
    ps += __shfl_xor(ps, off);
    pd += __shfl_xor(pd, off);
  }
  if (lane == 0) part[h] = pd / ps;
  __syncthreads();
  if (threadIdx.x == 0)
    vm[q] = (part[0] + part[1] + part[2] + part[3]) * (1.0f / 1024.0f);
}

extern "C" void kernel_launch(void* const* d_in, const int* in_sizes, int n_in,
                              void* d_out, int out_size, void* d_ws, size_t ws_size,
                              hipStream_t stream) {
  const float* q     = (const float*)d_in[0];
  const float* k     = (const float*)d_in[1];
  const float* v     = (const float*)d_in[2];
  const float* bias  = (const float*)d_in[3];
  const int*   mask  = (const int*)d_in[4];
  const float* Wq    = (const float*)d_in[5];
  const float* bq    = (const float*)d_in[6];
  const float* Wk    = (const float*)d_in[7];
  const float* bk    = (const float*)d_in[8];
  const float* Wbias = (const float*)d_in[9];
  const float* bbias = (const float*)d_in[10];
  const float* Wqo   = (const float*)d_in[11];
  const float* bqo   = (const float*)d_in[12];
  const float* Wko   = (const float*)d_in[13];
  const float* bko   = (const float*)d_in[14];
  const float* g_q   = (const float*)d_in[15];
  const float* be_q  = (const float*)d_in[16];
  const float* g_k   = (const float*)d_in[17];
  const float* be_k  = (const float*)d_in[18];
  const float* Wbo   = (const float*)d_in[19];
  const float* bbo   = (const float*)d_in[20];

  float* out = (float*)d_out;
  float* ws  = (float*)d_ws;
  float* projq = ws;                 // 1024x256
  float* projk = ws + 262144;        // 1024x256
  float* qo    = ws + 524288;        // 1024x256
  float* ko    = ws + 786432;        // 1024x256
  float* diffs = ws + 1048576;       // 4 x 1024 x 1024 (reused in-place as logits)
  float* svec  = ws + 5242880;       // 1024
  float* Mmat  = ws + 5243904;       // 41 x 40 composite

  float* q_out    = out;             // 1024x256
  float* k_out    = out + 262144;    // 1024x256
  float* vmean    = out + 524288;    // 1024
  float* bias_out = out + 525312;    // 1024x1024x40

  svec_kernel<<<1024, 64, 0, stream>>>(v, svec);
  mprec_kernel<<<41, 64, 0, stream>>>(Wbias, bbias, Wbo, Mmat);
  gemm1024<<<dim3(4, 16), 256, 0, stream>>>(q, Wq, bq, projq, 0);
  gemm1024<<<dim3(4, 16), 256, 0, stream>>>(k, Wk, bk, projk, 0);
  gemm1024<<<dim3(4, 16), 256, 0, stream>>>(projq, Wqo, bqo, qo, 1);
  gemm1024<<<dim3(4, 16), 256, 0, stream>>>(projk, Wko, bko, ko, 1);
  ln_epilogue<<<1024, 256, 0, stream>>>(q, qo, g_q, be_q, q_out);
  ln_epilogue<<<1024, 256, 0, stream>>>(k, ko, g_k, be_k, k_out);
  bias_mfma<<<1024, 256, 0, stream>>>(bias, Wbias, bbias, Mmat, bbo, diffs, bias_out);
  scores_kernel<<<dim3(16, 16, 4), 256, 0, stream>>>(projq, projk, mask, diffs);
  softmax_dot<<<1024, 256, 0, stream>>>(diffs, svec, vmean);
}

// Round 10
// 174.614 us; speedup vs baseline: 1.6477x; 1.2590x over previous
//
#include <hip/hip_runtime.h>
#include <hip/hip_bf16.h>
#include <math.h>

#define NEGV -9e15f

typedef short bf16x8 __attribute__((ext_vector_type(8)));
typedef float f32x4 __attribute__((ext_vector_type(4)));

__device__ __forceinline__ unsigned short f2bf(float x) {
  unsigned u = __float_as_uint(x);
  u += 0x7fffu + ((u >> 16) & 1u);
  return (unsigned short)(u >> 16);
}

__device__ __forceinline__ unsigned pk2(float a, float b) {
  __hip_bfloat162 h = __float22bfloat162_rn(make_float2(a, b));
  unsigned u;
  __builtin_memcpy(&u, &h, 4);
  return u;
}

// branchless mish: x * n/(n+2), n = u(u+2), u = e^min(x,30)
__device__ __forceinline__ float mishf(float x) {
  float u = __expf(fminf(x, 30.0f));
  float n = u * (u + 2.0f);
  return x * __fdividef(n, n + 2.0f);
}

// ---------------- prep: svec rows (bid<1024) + M composite rows (bid>=1024) ----------------
__global__ void prep_kernel(const float* __restrict__ v, float* __restrict__ s,
                            const float* __restrict__ Wb, const float* __restrict__ bb,
                            const float* __restrict__ Wo, float* __restrict__ M) {
  int bid = blockIdx.x;
  int lane = threadIdx.x;  // 64
  if (bid < 1024) {
    float4 a = *reinterpret_cast<const float4*>(v + (size_t)bid * 256 + lane * 4);
    float x = a.x + a.y + a.z + a.w;
    for (int off = 32; off; off >>= 1) x += __shfl_down(x, off);
    if (lane == 0) s[bid] = x;
  } else {
    int i = bid - 1024;  // 0..40
    if (lane >= 40) return;
    float acc = 0.0f;
    for (int k = 0; k < 160; ++k) {
      float w = (i < 40) ? Wb[i * 160 + k] : bb[k];
      acc = fmaf(w, Wo[k * 40 + lane], acc);
    }
    M[i * 40 + lane] = acc;
  }
}

// ---------------- paired GEMM: z selects (A,W,bvec,C); C = A @ W(perm) + bvec ----------------
__global__ __launch_bounds__(256) void gemm_pair(
    const float* __restrict__ A0, const float* __restrict__ W0,
    const float* __restrict__ bv0, float* __restrict__ C0,
    const float* __restrict__ A1, const float* __restrict__ W1,
    const float* __restrict__ bv1, float* __restrict__ C1, int perm) {
  const float* A = blockIdx.z ? A1 : A0;
  const float* W = blockIdx.z ? W1 : W0;
  const float* bvec = blockIdx.z ? bv1 : bv0;
  float* C = blockIdx.z ? C1 : C0;
  __shared__ float sAT[16][68];
  __shared__ float sW[16][68];
  int tid = threadIdx.x;
  int c0 = blockIdx.x * 64, r0 = blockIdx.y * 64;
  int ty = tid >> 4, tx = tid & 15;
  float acc[4][4] = {};
  for (int k0 = 0; k0 < 256; k0 += 16) {
    {
      int r = tid >> 2, jq = tid & 3;
      float4 a4 = *reinterpret_cast<const float4*>(A + (size_t)(r0 + r) * 256 + k0 + jq * 4);
      sAT[jq * 4 + 0][r] = a4.x;
      sAT[jq * 4 + 1][r] = a4.y;
      sAT[jq * 4 + 2][r] = a4.z;
      sAT[jq * 4 + 3][r] = a4.w;
    }
    {
      int kk = tid >> 4, cq = tid & 15;
      int gk = k0 + kk;
      int row = perm ? ((gk & 63) * 4 + (gk >> 6)) : gk;
      float4 w4 = *reinterpret_cast<const float4*>(W + (size_t)row * 256 + c0 + cq * 4);
      *reinterpret_cast<float4*>(&sW[kk][cq * 4]) = w4;
    }
    __syncthreads();
#pragma unroll
    for (int kk = 0; kk < 16; ++kk) {
      float4 av = *reinterpret_cast<const float4*>(&sAT[kk][ty * 4]);
      float4 bv = *reinterpret_cast<const float4*>(&sW[kk][tx * 4]);
      float a[4] = {av.x, av.y, av.z, av.w};
      float b[4] = {bv.x, bv.y, bv.z, bv.w};
#pragma unroll
      for (int i = 0; i < 4; ++i)
#pragma unroll
        for (int j = 0; j < 4; ++j) acc[i][j] = fmaf(a[i], b[j], acc[i][j]);
    }
    __syncthreads();
  }
#pragma unroll
  for (int i = 0; i < 4; ++i) {
    int rr = r0 + ty * 4 + i, cc = c0 + tx * 4;
    float4 o;
    o.x = acc[i][0] + bvec[cc + 0];
    o.y = acc[i][1] + bvec[cc + 1];
    o.z = acc[i][2] + bvec[cc + 2];
    o.w = acc[i][3] + bvec[cc + 3];
    *reinterpret_cast<float4*>(C + (size_t)rr * 256 + cc) = o;
  }
}

// ---------------- paired LN: out = LN(x0 + mish(y)) * g + be; y selects q/k ----------------
__global__ __launch_bounds__(256) void ln_pair(
    const float* __restrict__ x0q, const float* __restrict__ yq,
    const float* __restrict__ gq, const float* __restrict__ beq,
    float* __restrict__ outq,
    const float* __restrict__ x0k, const float* __restrict__ yk,
    const float* __restrict__ gk, const float* __restrict__ bek,
    float* __restrict__ outk) {
  const float* x0 = blockIdx.y ? x0k : x0q;
  const float* y  = blockIdx.y ? yk  : yq;
  const float* g  = blockIdx.y ? gk  : gq;
  const float* be = blockIdx.y ? bek : beq;
  float* out      = blockIdx.y ? outk : outq;
  __shared__ float r1[5], r2[5];
  int r = blockIdx.x, t = threadIdx.x;
  int wid = t >> 6, lane = t & 63;
  float x = x0[(size_t)r * 256 + t] + mishf(y[(size_t)r * 256 + t]);
  float a = x, b = x * x;
  for (int off = 32; off; off >>= 1) {
    a += __shfl_down(a, off);
    b += __shfl_down(b, off);
  }
  if (lane == 0) { r1[wid] = a; r2[wid] = b; }
  __syncthreads();
  if (t == 0) {
    r1[4] = r1[0] + r1[1] + r1[2] + r1[3];
    r2[4] = r2[0] + r2[1] + r2[2] + r2[3];
  }
  __syncthreads();
  float m = r1[4] * (1.0f / 256.0f);
  float var = r2[4] * (1.0f / 256.0f) - m * m;
  out[(size_t)r * 256 + t] = (x - m) * rsqrtf(var + 1e-5f) * g[t] + be[t];
}

// ---------------- fused bias path v3: regs-only, 2 tiles/iter (unchanged winner) ----------------
#define TILE_BODY(XF0, XF1, P0) do {                                                   \
    float hv0, hv1, hv2, hv3;                                                          \
    {                                                                                  \
      f32x4 z = {0.0f, 0.0f, 0.0f, 0.0f};                                              \
      f32x4 q;                                                                         \
      float cs2, cs7;                                                                  \
      q = __builtin_amdgcn_mfma_f32_16x16x32_bf16(wf[0][0], XF0, z, 0, 0, 0);          \
      q = __builtin_amdgcn_mfma_f32_16x16x32_bf16(wf[0][1], XF1, q, 0, 0, 0);          \
      hv0 = q[0]*q[0] + q[1]*q[1] + q[2]*q[2] + q[3]*q[3];                             \
      q = __builtin_amdgcn_mfma_f32_16x16x32_bf16(wf[1][0], XF0, z, 0, 0, 0);          \
      q = __builtin_amdgcn_mfma_f32_16x16x32_bf16(wf[1][1], XF1, q, 0, 0, 0);          \
      hv0 += q[0]*q[0] + q[1]*q[1] + q[2]*q[2] + q[3]*q[3];                            \
      q = __builtin_amdgcn_mfma_f32_16x16x32_bf16(wf[2][0], XF0, z, 0, 0, 0);          \
      q = __builtin_amdgcn_mfma_f32_16x16x32_bf16(wf[2][1], XF1, q, 0, 0, 0);          \
      cs2 = q[0]*q[0] + q[1]*q[1] + q[2]*q[2] + q[3]*q[3];                             \
      q = __builtin_amdgcn_mfma_f32_16x16x32_bf16(wf[3][0], XF0, z, 0, 0, 0);          \
      q = __builtin_amdgcn_mfma_f32_16x16x32_bf16(wf[3][1], XF1, q, 0, 0, 0);          \
      hv1 = q[0]*q[0] + q[1]*q[1] + q[2]*q[2] + q[3]*q[3];                             \
      q = __builtin_amdgcn_mfma_f32_16x16x32_bf16(wf[4][0], XF0, z, 0, 0, 0);          \
      q = __builtin_amdgcn_mfma_f32_16x16x32_bf16(wf[4][1], XF1, q, 0, 0, 0);          \
      hv1 += q[0]*q[0] + q[1]*q[1] + q[2]*q[2] + q[3]*q[3];                            \
      q = __builtin_amdgcn_mfma_f32_16x16x32_bf16(wf[5][0], XF0, z, 0, 0, 0);          \
      q = __builtin_amdgcn_mfma_f32_16x16x32_bf16(wf[5][1], XF1, q, 0, 0, 0);          \
      hv2 = q[0]*q[0] + q[1]*q[1] + q[2]*q[2] + q[3]*q[3];                             \
      q = __builtin_amdgcn_mfma_f32_16x16x32_bf16(wf[6][0], XF0, z, 0, 0, 0);          \
      q = __builtin_amdgcn_mfma_f32_16x16x32_bf16(wf[6][1], XF1, q, 0, 0, 0);          \
      hv2 += q[0]*q[0] + q[1]*q[1] + q[2]*q[2] + q[3]*q[3];                            \
      q = __builtin_amdgcn_mfma_f32_16x16x32_bf16(wf[7][0], XF0, z, 0, 0, 0);          \
      q = __builtin_amdgcn_mfma_f32_16x16x32_bf16(wf[7][1], XF1, q, 0, 0, 0);          \
      cs7 = q[0]*q[0] + q[1]*q[1] + q[2]*q[2] + q[3]*q[3];                             \
      q = __builtin_amdgcn_mfma_f32_16x16x32_bf16(wf[8][0], XF0, z, 0, 0, 0);          \
      q = __builtin_amdgcn_mfma_f32_16x16x32_bf16(wf[8][1], XF1, q, 0, 0, 0);          \
      hv3 = q[0]*q[0] + q[1]*q[1] + q[2]*q[2] + q[3]*q[3];                             \
      q = __builtin_amdgcn_mfma_f32_16x16x32_bf16(wf[9][0], XF0, z, 0, 0, 0);          \
      q = __builtin_amdgcn_mfma_f32_16x16x32_bf16(wf[9][1], XF1, q, 0, 0, 0);          \
      hv3 += q[0]*q[0] + q[1]*q[1] + q[2]*q[2] + q[3]*q[3];                            \
      float csa = (g < 2) ? cs2 : 0.0f;                                                \
      float csb = (g < 2) ? 0.0f : cs2;                                                \
      float csc = (g < 2) ? cs7 : 0.0f;                                                \
      float csd = (g < 2) ? 0.0f : cs7;                                                \
      hv0 += csa; hv1 += csb; hv2 += csc; hv3 += csd;                                  \
    }                                                                                  \
    hv0 += __shfl_xor(hv0, 16); hv0 += __shfl_xor(hv0, 32);                            \
    hv1 += __shfl_xor(hv1, 16); hv1 += __shfl_xor(hv1, 32);                            \
    hv2 += __shfl_xor(hv2, 16); hv2 += __shfl_xor(hv2, 32);                            \
    hv3 += __shfl_xor(hv3, 16); hv3 += __shfl_xor(hv3, 32);                            \
    float ss = (g == 0) ? hv0 : (g == 1) ? hv1 : (g == 2) ? hv2 : hv3;                 \
    diffs[(size_t)g * (1024 * 1024) + (P0) + r] = sqrtf(ss);                           \
    f32x4 o0 = bo40, o1 = bo41, o2 = bo42;                                             \
    o0 = __builtin_amdgcn_mfma_f32_16x16x32_bf16(mf[0][0], XF0, o0, 0, 0, 0);          \
    o1 = __builtin_amdgcn_mfma_f32_16x16x32_bf16(mf[1][0], XF0, o1, 0, 0, 0);          \
    o2 = __builtin_amdgcn_mfma_f32_16x16x32_bf16(mf[2][0], XF0, o2, 0, 0, 0);          \
    o0 = __builtin_amdgcn_mfma_f32_16x16x32_bf16(mf[0][1], XF1, o0, 0, 0, 0);          \
    o1 = __builtin_amdgcn_mfma_f32_16x16x32_bf16(mf[1][1], XF1, o1, 0, 0, 0);          \
    o2 = __builtin_amdgcn_mfma_f32_16x16x32_bf16(mf[2][1], XF1, o2, 0, 0, 0);          \
    float* bp = bout + (size_t)((P0) + r) * 40;                                        \
    float4 st;                                                                         \
    st.x = mishf(o0[0]); st.y = mishf(o0[1]);                                          \
    st.z = mishf(o0[2]); st.w = mishf(o0[3]);                                          \
    *reinterpret_cast<float4*>(bp + 4 * g) = st;                                       \
    st.x = mishf(o1[0]); st.y = mishf(o1[1]);                                          \
    st.z = mishf(o1[2]); st.w = mishf(o1[3]);                                          \
    *reinterpret_cast<float4*>(bp + 16 + 4 * g) = st;                                  \
    if (g < 2) {                                                                       \
      st.x = mishf(o2[0]); st.y = mishf(o2[1]);                                        \
      st.z = mishf(o2[2]); st.w = mishf(o2[3]);                                        \
      *reinterpret_cast<float4*>(bp + 32 + 4 * g) = st;                                \
    }                                                                                  \
  } while (0)

__global__ __launch_bounds__(256, 2) void bias_mfma(
    const float* __restrict__ bias, const float* __restrict__ Wb,
    const float* __restrict__ bb, const float* __restrict__ Mmat,
    const float* __restrict__ bo, float* __restrict__ diffs,
    float* __restrict__ bout) {
  int tid = threadIdx.x;
  int wv = tid >> 6, lane = tid & 63;
  int r = lane & 15, g = lane >> 4;

  // Wb' fragments (A-operand): wf[n0][ks]; k=40 slot carries bb (bias fold)
  bf16x8 wf[10][2];
#pragma unroll
  for (int n0 = 0; n0 < 10; ++n0)
#pragma unroll
    for (int ks = 0; ks < 2; ++ks)
#pragma unroll
      for (int jj = 0; jj < 8; ++jj) {
        int k = ks * 32 + g * 8 + jj;
        int c = n0 * 16 + r;
        float w = (k < 40) ? Wb[k * 160 + c] : ((k == 40) ? bb[c] : 0.0f);
        wf[n0][ks][jj] = (short)f2bf(w);
      }
  // M^T fragments (A-operand): mf[n][ks]
  bf16x8 mf[3][2];
#pragma unroll
  for (int n = 0; n < 3; ++n)
#pragma unroll
    for (int ks = 0; ks < 2; ++ks)
#pragma unroll
      for (int jj = 0; jj < 8; ++jj) {
        int k = ks * 32 + g * 8 + jj;
        int c = n * 16 + r;
        float w = (k <= 40 && c < 40) ? Mmat[k * 40 + c] : 0.0f;
        mf[n][ks][jj] = (short)f2bf(w);
      }
  // bo as per-lane f32x4: cols 16n + 4g .. +3
  f32x4 bo40, bo41, bo42;
  {
    float4 t0 = *reinterpret_cast<const float4*>(bo + 4 * g);
    float4 t1 = *reinterpret_cast<const float4*>(bo + 16 + 4 * g);
    bo40[0] = t0.x; bo40[1] = t0.y; bo40[2] = t0.z; bo40[3] = t0.w;
    bo41[0] = t1.x; bo41[1] = t1.y; bo41[2] = t1.z; bo41[3] = t1.w;
    if (g < 2) {
      float4 t2 = *reinterpret_cast<const float4*>(bo + 32 + 4 * g);
      bo42[0] = t2.x; bo42[1] = t2.y; bo42[2] = t2.z; bo42[3] = t2.w;
    } else {
      bo42[0] = 0.0f; bo42[1] = 0.0f; bo42[2] = 0.0f; bo42[3] = 0.0f;
    }
  }

  size_t row0 = ((size_t)blockIdx.x * 4 + wv) * 256;  // 8 iters x 2 tiles x 16 rows

  // prefetch tiles 0,1
  const float* xr0 = bias + (row0 + r) * 40;
  const float* xr1 = bias + (row0 + 16 + r) * 40;
  float4 x0A = *reinterpret_cast<const float4*>(xr0 + g * 8);
  float4 x0B = *reinterpret_cast<const float4*>(xr0 + g * 8 + 4);
  float4 x0C = *reinterpret_cast<const float4*>(xr0 + 32);
  float4 x0D = *reinterpret_cast<const float4*>(xr0 + 36);
  float4 x1A = *reinterpret_cast<const float4*>(xr1 + g * 8);
  float4 x1B = *reinterpret_cast<const float4*>(xr1 + g * 8 + 4);
  float4 x1C = *reinterpret_cast<const float4*>(xr1 + 32);
  float4 x1D = *reinterpret_cast<const float4*>(xr1 + 36);

#pragma unroll 1
  for (int it = 0; it < 8; ++it) {
    const size_t p0 = row0 + (size_t)it * 32;
    bf16x8 a0f0, a0f1, a1f0, a1f1;
    {
      uint4 t0 = {pk2(x0A.x, x0A.y), pk2(x0A.z, x0A.w), pk2(x0B.x, x0B.y), pk2(x0B.z, x0B.w)};
      unsigned d0 = (g == 1) ? 0x00003f80u : pk2(x0C.x, x0C.y);
      uint4 t1 = {d0, pk2(x0C.z, x0C.w), pk2(x0D.x, x0D.y), pk2(x0D.z, x0D.w)};
      __builtin_memcpy(&a0f0, &t0, 16);
      __builtin_memcpy(&a0f1, &t1, 16);
      uint4 t2 = {pk2(x1A.x, x1A.y), pk2(x1A.z, x1A.w), pk2(x1B.x, x1B.y), pk2(x1B.z, x1B.w)};
      unsigned d1 = (g == 1) ? 0x00003f80u : pk2(x1C.x, x1C.y);
      uint4 t3 = {d1, pk2(x1C.z, x1C.w), pk2(x1D.x, x1D.y), pk2(x1D.z, x1D.w)};
      __builtin_memcpy(&a1f0, &t2, 16);
      __builtin_memcpy(&a1f1, &t3, 16);
    }
    if (it < 7) {
      const float* nr0 = bias + (p0 + 32 + r) * 40;
      const float* nr1 = bias + (p0 + 48 + r) * 40;
      x0A = *reinterpret_cast<const float4*>(nr0 + g * 8);
      x0B = *reinterpret_cast<const float4*>(nr0 + g * 8 + 4);
      x0C = *reinterpret_cast<const float4*>(nr0 + 32);
      x0D = *reinterpret_cast<const float4*>(nr0 + 36);
      x1A = *reinterpret_cast<const float4*>(nr1 + g * 8);
      x1B = *reinterpret_cast<const float4*>(nr1 + g * 8 + 4);
      x1C = *reinterpret_cast<const float4*>(nr1 + 32);
      x1D = *reinterpret_cast<const float4*>(nr1 + 36);
    }
    TILE_BODY(a0f0, a0f1, p0);
    TILE_BODY(a1f0, a1f1, p0 + 16);
  }
}

// ---------------- logits[h][q][k] = qk/8 + diffs, masked (in-place over diffs) ----------------
__global__ __launch_bounds__(256) void scores_kernel(
    const float* __restrict__ pq, const float* __restrict__ pk,
    const int* __restrict__ mask, float* __restrict__ logits) {
  __shared__ float sQT[64][68];
  __shared__ float sKT[64][68];
  int tid = threadIdx.x;
  int k0 = blockIdx.x * 64, q0 = blockIdx.y * 64, h = blockIdx.z;
  for (int i = tid; i < 1024; i += 256) {
    int r = i >> 4, dq = i & 15;
    float4 a = *reinterpret_cast<const float4*>(pq + (size_t)(q0 + r) * 256 + h * 64 + dq * 4);
    sQT[dq * 4 + 0][r] = a.x;
    sQT[dq * 4 + 1][r] = a.y;
    sQT[dq * 4 + 2][r] = a.z;
    sQT[dq * 4 + 3][r] = a.w;
    float4 b = *reinterpret_cast<const float4*>(pk + (size_t)(k0 + r) * 256 + h * 64 + dq * 4);
    sKT[dq * 4 + 0][r] = b.x;
    sKT[dq * 4 + 1][r] = b.y;
    sKT[dq * 4 + 2][r] = b.z;
    sKT[dq * 4 + 3][r] = b.w;
  }
  __syncthreads();
  int ty = tid >> 4, tx = tid & 15;
  float acc[4][4] = {};
#pragma unroll 4
  for (int d = 0; d < 64; ++d) {
    float4 av = *reinterpret_cast<const float4*>(&sQT[d][ty * 4]);
    float4 bv = *reinterpret_cast<const float4*>(&sKT[d][tx * 4]);
    float a[4] = {av.x, av.y, av.z, av.w};
    float b[4] = {bv.x, bv.y, bv.z, bv.w};
#pragma unroll
    for (int i = 0; i < 4; ++i)
#pragma unroll
      for (int j = 0; j < 4; ++j) acc[i][j] = fmaf(a[i], b[j], acc[i][j]);
  }
#pragma unroll
  for (int i = 0; i < 4; ++i) {
    int qq = q0 + ty * 4 + i;
    size_t base = (size_t)h * 1048576 + (size_t)qq * 1024 + k0 + tx * 4;
    float4 dv = *reinterpret_cast<const float4*>(logits + base);
    int4 mv = *reinterpret_cast<const int4*>(mask + (size_t)qq * 1024 + k0 + tx * 4);
    float4 o;
    o.x = (mv.x == 0) ? NEGV : fmaf(acc[i][0], 0.125f, dv.x);
    o.y = (mv.y == 0) ? NEGV : fmaf(acc[i][1], 0.125f, dv.y);
    o.z = (mv.z == 0) ? NEGV : fmaf(acc[i][2], 0.125f, dv.z);
    o.w = (mv.w == 0) ? NEGV : fmaf(acc[i][3], 0.125f, dv.w);
    *reinterpret_cast<float4*>(logits + base) = o;
  }
}

// ---------------- wave per (q, head): softmax over k, dot with s ----------------
__global__ __launch_bounds__(256) void softmax_dot(
    const float* __restrict__ logits, const float* __restrict__ sv,
    float* __restrict__ vm) {
  __shared__ float part[4];
  int q = blockIdx.x;
  int h = threadIdx.x >> 6, lane = threadIdx.x & 63;
  const float* lp = logits + (size_t)h * 1048576 + (size_t)q * 1024;
  float4 lv0 = *reinterpret_cast<const float4*>(lp + lane * 4);
  float4 lv1 = *reinterpret_cast<const float4*>(lp + 256 + lane * 4);
  float4 lv2 = *reinterpret_cast<const float4*>(lp + 512 + lane * 4);
  float4 lv3 = *reinterpret_cast<const float4*>(lp + 768 + lane * 4);
  float4 s0 = *reinterpret_cast<const float4*>(sv + lane * 4);
  float4 s1 = *reinterpret_cast<const float4*>(sv + 256 + lane * 4);
  float4 s2 = *reinterpret_cast<const float4*>(sv + 512 + lane * 4);
  float4 s3 = *reinterpret_cast<const float4*>(sv + 768 + lane * 4);
  float m = fmaxf(fmaxf(fmaxf(lv0.x, lv0.y), fmaxf(lv0.z, lv0.w)),
                  fmaxf(fmaxf(lv1.x, lv1.y), fmaxf(lv1.z, lv1.w)));
  m = fmaxf(m, fmaxf(fmaxf(fmaxf(lv2.x, lv2.y), fmaxf(lv2.z, lv2.w)),
                     fmaxf(fmaxf(lv3.x, lv3.y), fmaxf(lv3.z, lv3.w))));
#pragma unroll
  for (int off = 32; off; off >>= 1) m = fmaxf(m, __shfl_xor(m, off));
  float ps = 0.0f, pd = 0.0f;
  {
    float e;
    e = __expf(lv0.x - m); ps += e; pd = fmaf(e, s0.x, pd);
    e = __expf(lv0.y - m); ps += e; pd = fmaf(e, s0.y, pd);
    e = __expf(lv0.z - m); ps += e; pd = fmaf(e, s0.z, pd);
    e = __expf(lv0.w - m); ps += e; pd = fmaf(e, s0.w, pd);
    e = __expf(lv1.x - m); ps += e; pd = fmaf(e, s1.x, pd);
    e = __expf(lv1.y - m); ps += e; pd = fmaf(e, s1.y, pd);
    e = __expf(lv1.z - m); ps += e; pd = fmaf(e, s1.z, pd);
    e = __expf(lv1.w - m); ps += e; pd = fmaf(e, s1.w, pd);
    e = __expf(lv2.x - m); ps += e; pd = fmaf(e, s2.x, pd);
    e = __expf(lv2.y - m); ps += e; pd = fmaf(e, s2.y, pd);
    e = __expf(lv2.z - m); ps += e; pd = fmaf(e, s2.z, pd);
    e = __expf(lv2.w - m); ps += e; pd = fmaf(e, s2.w, pd);
    e = __expf(lv3.x - m); ps += e; pd = fmaf(e, s3.x, pd);
    e = __expf(lv3.y - m); ps += e; pd = fmaf(e, s3.y, pd);
    e = __expf(lv3.z - m); ps += e; pd = fmaf(e, s3.z, pd);
    e = __expf(lv3.w - m); ps += e; pd = fmaf(e, s3.w, pd);
  }
#pragma unroll
  for (int off = 32; off; off >>= 1) {
    ps += __shfl_xor(ps, off);
    pd += __shfl_xor(pd, off);
  }
  if (lane == 0) part[h] = pd / ps;
  __syncthreads();
  if (threadIdx.x == 0)
    vm[q] = (part[0] + part[1] + part[2] + part[3]) * (1.0f / 1024.0f);
}

extern "C" void kernel_launch(void* const* d_in, const int* in_sizes, int n_in,
                              void* d_out, int out_size, void* d_ws, size_t ws_size,
                              hipStream_t stream) {
  const float* q     = (const float*)d_in[0];
  const float* k     = (const float*)d_in[1];
  const float* v     = (const float*)d_in[2];
  const float* bias  = (const float*)d_in[3];
  const int*   mask  = (const int*)d_in[4];
  const float* Wq    = (const float*)d_in[5];
  const float* bq    = (const float*)d_in[6];
  const float* Wk    = (const float*)d_in[7];
  const float* bk    = (const float*)d_in[8];
  const float* Wbias = (const float*)d_in[9];
  const float* bbias = (const float*)d_in[10];
  const float* Wqo   = (const float*)d_in[11];
  const float* bqo   = (const float*)d_in[12];
  const float* Wko   = (const float*)d_in[13];
  const float* bko   = (const float*)d_in[14];
  const float* g_q   = (const float*)d_in[15];
  const float* be_q  = (const float*)d_in[16];
  const float* g_k   = (const float*)d_in[17];
  const float* be_k  = (const float*)d_in[18];
  const float* Wbo   = (const float*)d_in[19];
  const float* bbo   = (const float*)d_in[20];

  float* out = (float*)d_out;
  float* ws  = (float*)d_ws;
  float* projq = ws;                 // 1024x256
  float* projk = ws + 262144;        // 1024x256
  float* qo    = ws + 524288;        // 1024x256
  float* ko    = ws + 786432;        // 1024x256
  float* diffs = ws + 1048576;       // 4 x 1024 x 1024 (reused in-place as logits)
  float* svec  = ws + 5242880;       // 1024
  float* Mmat  = ws + 5243904;       // 41 x 40 composite

  float* q_out    = out;             // 1024x256
  float* k_out    = out + 262144;    // 1024x256
  float* vmean    = out + 524288;    // 1024
  float* bias_out = out + 525312;    // 1024x1024x40

  prep_kernel<<<1065, 64, 0, stream>>>(v, svec, Wbias, bbias, Wbo, Mmat);
  gemm_pair<<<dim3(4, 16, 2), 256, 0, stream>>>(q, Wq, bq, projq,
                                                k, Wk, bk, projk, 0);
  bias_mfma<<<1024, 256, 0, stream>>>(bias, Wbias, bbias, Mmat, bbo, diffs, bias_out);
  gemm_pair<<<dim3(4, 16, 2), 256, 0, stream>>>(projq, Wqo, bqo, qo,
                                                projk, Wko, bko, ko, 1);
  ln_pair<<<dim3(1024, 2), 256, 0, stream>>>(q, qo, g_q, be_q, q_out,
                                             k, ko, g_k, be_k, k_out);
  scores_kernel<<<dim3(16, 16, 4), 256, 0, stream>>>(projq, projk, mask, diffs);
  softmax_dot<<<1024, 256, 0, stream>>>(diffs, svec, vmean);
}